// Round 2
// baseline (599.847 us; speedup 1.0000x reference)
//
#include <hip/hip_runtime.h>

#define Bc 512
#define Lc 512
#define Tc 128

// raw barrier: drain LDS ops, do NOT drain vmcnt (global prefetches stay in flight)
__device__ __forceinline__ void bar_lgkm() {
  asm volatile("s_waitcnt lgkmcnt(0)\n\ts_barrier" ::: "memory");
}

__global__ __launch_bounds__(128, 1)
void crf_forward(const float* __restrict__ x,      // [B,L,T]
                 const float* __restrict__ trans,  // [T,T]
                 const float* __restrict__ startT, // [T]
                 const float* __restrict__ endT,   // [T]
                 const int*   __restrict__ labels, // [B,L]
                 const int*   __restrict__ mask,   // [B,L]
                 float* __restrict__ diff_out,     // [B] logZ - score
                 float* __restrict__ msum_out)     // [B] per-batch mask sum
{
  __shared__ __align__(16) float pbuf[2][Tc];
  __shared__ float aslot[2];
  __shared__ float sred[128];
  __shared__ int   mask_s[Lc];
  __shared__ float s_score;
  __shared__ int   s_msum;

  const int j = threadIdx.x;        // 0..127 (tag column)
  const int b = blockIdx.x;         // batch
  const int lane = j & 63;
  const int wid  = j >> 6;
  const float* xb = x + (size_t)b * (Lc * Tc);
  const int* lb = labels + b * Lc;
  const int* mk = mask   + b * Lc;

  // ---- stage mask row into LDS ----
  for (int t = j; t < Lc; t += 128) mask_s[t] = mk[t];

  // ---- E column j in NAMED registers: eK holds exp(trans[4K+0..3][j]) ----
  const float* tcol = trans + j;
#define LOADE(K) float4 e##K; \
  e##K.x = __expf(tcol[(4*K+0)*Tc]); \
  e##K.y = __expf(tcol[(4*K+1)*Tc]); \
  e##K.z = __expf(tcol[(4*K+2)*Tc]); \
  e##K.w = __expf(tcol[(4*K+3)*Tc]);
  LOADE(0)  LOADE(1)  LOADE(2)  LOADE(3)
  LOADE(4)  LOADE(5)  LOADE(6)  LOADE(7)
  LOADE(8)  LOADE(9)  LOADE(10) LOADE(11)
  LOADE(12) LOADE(13) LOADE(14) LOADE(15)
  LOADE(16) LOADE(17) LOADE(18) LOADE(19)
  LOADE(20) LOADE(21) LOADE(22) LOADE(23)
  LOADE(24) LOADE(25) LOADE(26) LOADE(27)
  LOADE(28) LOADE(29) LOADE(30) LOADE(31)
#undef LOADE
  __syncthreads();

  // ---- mask sum ----
  int mpart = 0;
  for (int t = j; t < Lc; t += 128) mpart += mask_s[t];
  sred[j] = (float)mpart;
  __syncthreads();
#pragma unroll
  for (int s = 64; s > 0; s >>= 1) {
    if (j < s) sred[j] += sred[j + s];
    __syncthreads();
  }
  if (j == 0) s_msum = (int)sred[0];
  __syncthreads();
  const int msum = s_msum;

  // ---- gold-path score ----
  float spart = 0.f;
  for (int t = j; t < Lc - 1; t += 128) {
    int l0 = lb[t], l1 = lb[t + 1];
    float m0 = (float)mask_s[t], m1 = (float)mask_s[t + 1];
    spart += trans[l0 * Tc + l1] * m1 + xb[t * Tc + l0] * m0;
  }
  __syncthreads();
  sred[j] = spart;
  __syncthreads();
#pragma unroll
  for (int s = 64; s > 0; s >>= 1) {
    if (j < s) sred[j] += sred[j + s];
    __syncthreads();
  }
  if (j == 0) {
    int last_idx = msum - 1;
    int lt = lb[last_idx];
    s_score = sred[0] + startT[lb[0]] + endT[lt]
            + xb[(Lc - 1) * Tc + lt] * (float)mask_s[Lc - 1];
  }

  // ---- forward recurrence (1 barrier/step, double-buffered p) ----
  float a = startT[j] + xb[j];        // alpha_0[j]
  if (j == 0) aslot[1] = a;
  float x0 = xb[1 * Tc + j];          // emit prefetch, 2 steps deep
  float x1 = xb[2 * Tc + j];
  __syncthreads();                    // publishes aslot + s_score
  float m = aslot[1];                 // shift for first step = alpha_0[0] (exact)

  for (int t = 1; t < Lc; ++t) {
    const int c = t & 1;
    int tpre = (t + 2 < Lc) ? (t + 2) : (Lc - 1);
    float x2 = xb[tpre * Tc + j];     // stays in flight across raw barriers
    const float s = m;                // shift used THIS step (α_{t-2}[0], exact lse shift)
    float pj = __expf(a - s);
    pbuf[c][j] = pj;
    if (j == 0) aslot[c] = a;         // publish α_{t-1}[0] for next step's shift
    bar_lgkm();
    m = aslot[c];

    const float4* P4 = (const float4*)pbuf[c];
    float acc0 = 0.f, acc1 = 0.f, acc2 = 0.f, acc3 = 0.f;
#define BLK(K, EV, ACC) { float4 pv = P4[K]; \
    ACC = fmaf(EV.x, pv.x, ACC); ACC = fmaf(EV.y, pv.y, ACC); \
    ACC = fmaf(EV.z, pv.z, ACC); ACC = fmaf(EV.w, pv.w, ACC); }
    BLK(0,  e0,  acc0) BLK(1,  e1,  acc1) BLK(2,  e2,  acc2) BLK(3,  e3,  acc3)
    BLK(4,  e4,  acc0) BLK(5,  e5,  acc1) BLK(6,  e6,  acc2) BLK(7,  e7,  acc3)
    BLK(8,  e8,  acc0) BLK(9,  e9,  acc1) BLK(10, e10, acc2) BLK(11, e11, acc3)
    BLK(12, e12, acc0) BLK(13, e13, acc1) BLK(14, e14, acc2) BLK(15, e15, acc3)
    BLK(16, e16, acc0) BLK(17, e17, acc1) BLK(18, e18, acc2) BLK(19, e19, acc3)
    BLK(20, e20, acc0) BLK(21, e21, acc1) BLK(22, e22, acc2) BLK(23, e23, acc3)
    BLK(24, e24, acc0) BLK(25, e25, acc1) BLK(26, e26, acc2) BLK(27, e27, acc3)
    BLK(28, e28, acc0) BLK(29, e29, acc1) BLK(30, e30, acc2) BLK(31, e31, acc3)
#undef BLK
    float acc = (acc0 + acc1) + (acc2 + acc3);
    float na = x0 + s + __logf(acc);
    a = mask_s[t] ? na : a;           // mask blend (mask in {0,1})
    x0 = x1; x1 = x2;
  }

  // ---- log_denominator = logsumexp_j(alpha + end) ----
  float v = a + endT[j];
  float wm = v;
#pragma unroll
  for (int off = 32; off; off >>= 1) wm = fmaxf(wm, __shfl_xor(wm, off));
  if (lane == 0) sred[wid] = wm;
  __syncthreads();
  float M = fmaxf(sred[0], sred[1]);
  float e = __expf(v - M);
  float wsum = e;
#pragma unroll
  for (int off = 32; off; off >>= 1) wsum += __shfl_xor(wsum, off);
  if (lane == 0) sred[2 + wid] = wsum;
  __syncthreads();
  if (j == 0) {
    float ld = M + __logf(sred[2] + sred[3]);
    diff_out[b] = ld - s_score;
    msum_out[b] = (float)msum;
  }
}

__global__ __launch_bounds__(512)
void crf_final(const float* __restrict__ diff, const float* __restrict__ msum,
               float* __restrict__ out)
{
  __shared__ float sd[512];
  __shared__ float sm[512];
  int t = threadIdx.x;
  sd[t] = diff[t];
  sm[t] = msum[t];
  __syncthreads();
  for (int s = 256; s > 0; s >>= 1) {
    if (t < s) { sd[t] += sd[t + s]; sm[t] += sm[t + s]; }
    __syncthreads();
  }
  if (t == 0) out[0] = sd[0] / sm[0];
}

extern "C" void kernel_launch(void* const* d_in, const int* in_sizes, int n_in,
                              void* d_out, int out_size, void* d_ws, size_t ws_size,
                              hipStream_t stream) {
  const float* x      = (const float*)d_in[0];
  const float* trans  = (const float*)d_in[1];
  const float* startT = (const float*)d_in[2];
  const float* endT   = (const float*)d_in[3];
  const int*   labels = (const int*)d_in[4];
  const int*   mask   = (const int*)d_in[5];
  float* out = (float*)d_out;
  float* ws  = (float*)d_ws;
  float* diff = ws;        // [512]
  float* msum = ws + Bc;   // [512]

  crf_forward<<<dim3(Bc), dim3(128), 0, stream>>>(
      x, trans, startT, endT, labels, mask, diff, msum);
  crf_final<<<dim3(1), dim3(512), 0, stream>>>(diff, msum, out);
}

// Round 3
// 596.560 us; speedup vs baseline: 1.0055x; 1.0055x over previous
//
#include <hip/hip_runtime.h>

#define Bc 512
#define Lc 512
#define Tc 128

// raw barrier: drain LDS ops, do NOT drain vmcnt (global prefetches stay in flight)
__device__ __forceinline__ void bar_lgkm() {
  asm volatile("s_waitcnt lgkmcnt(0)\n\ts_barrier" ::: "memory");
}

__global__ __launch_bounds__(128, 1)
void crf_forward(const float* __restrict__ x,      // [B,L,T]
                 const float* __restrict__ trans,  // [T,T]
                 const float* __restrict__ startT, // [T]
                 const float* __restrict__ endT,   // [T]
                 const int*   __restrict__ labels, // [B,L]
                 const int*   __restrict__ mask,   // [B,L]
                 float* __restrict__ diff_out,     // [B] logZ - score
                 float* __restrict__ msum_out)     // [B] per-batch mask sum
{
  __shared__ __align__(16) float pbuf[2][Tc];
  __shared__ float aslot[2];
  __shared__ float sred[128];
  __shared__ int   mask_s[Lc];
  __shared__ float s_score;
  __shared__ int   s_msum;

  const int j = threadIdx.x;        // 0..127 (tag column)
  const int b = blockIdx.x;         // batch
  const int lane = j & 63;
  const int wid  = j >> 6;
  const float* xb = x + (size_t)b * (Lc * Tc);
  const int* lb = labels + b * Lc;
  const int* mk = mask   + b * Lc;

  // ---- stage mask row into LDS ----
  for (int t = j; t < Lc; t += 128) mask_s[t] = mk[t];
  __syncthreads();

  // ---- mask sum ----
  int mpart = 0;
  for (int t = j; t < Lc; t += 128) mpart += mask_s[t];
  sred[j] = (float)mpart;
  __syncthreads();
#pragma unroll
  for (int s = 64; s > 0; s >>= 1) {
    if (j < s) sred[j] += sred[j + s];
    __syncthreads();
  }
  if (j == 0) s_msum = (int)sred[0];
  __syncthreads();
  const int msum = s_msum;

  // ---- gold-path score ----
  float spart = 0.f;
  for (int t = j; t < Lc - 1; t += 128) {
    int l0 = lb[t], l1 = lb[t + 1];
    float m0 = (float)mask_s[t], m1 = (float)mask_s[t + 1];
    spart += trans[l0 * Tc + l1] * m1 + xb[t * Tc + l0] * m0;
  }
  __syncthreads();
  sred[j] = spart;
  __syncthreads();
#pragma unroll
  for (int s = 64; s > 0; s >>= 1) {
    if (j < s) sred[j] += sred[j + s];
    __syncthreads();
  }
  if (j == 0) {
    int last_idx = msum - 1;
    int lt = lb[last_idx];
    s_score = sred[0] + startT[lb[0]] + endT[lt]
            + xb[(Lc - 1) * Tc + lt] * (float)mask_s[Lc - 1];
  }

  // ---- E column j in registers, PINNED so the scheduler cannot remat the
  //      load+exp inside the loop (that was the round-1/2 disaster: VGPR=92).
  const float* tcol = trans + j;
#define LOADE(K) float4 e##K; \
  e##K.x = __expf(tcol[(4*K+0)*Tc]); \
  e##K.y = __expf(tcol[(4*K+1)*Tc]); \
  e##K.z = __expf(tcol[(4*K+2)*Tc]); \
  e##K.w = __expf(tcol[(4*K+3)*Tc]); \
  asm volatile("" : "+v"(e##K.x), "+v"(e##K.y), "+v"(e##K.z), "+v"(e##K.w));
  LOADE(0)  LOADE(1)  LOADE(2)  LOADE(3)
  LOADE(4)  LOADE(5)  LOADE(6)  LOADE(7)
  LOADE(8)  LOADE(9)  LOADE(10) LOADE(11)
  LOADE(12) LOADE(13) LOADE(14) LOADE(15)
  LOADE(16) LOADE(17) LOADE(18) LOADE(19)
  LOADE(20) LOADE(21) LOADE(22) LOADE(23)
  LOADE(24) LOADE(25) LOADE(26) LOADE(27)
  LOADE(28) LOADE(29) LOADE(30) LOADE(31)
#undef LOADE

  // ---- forward recurrence (1 barrier/step, double-buffered p) ----
  float a = startT[j] + xb[j];        // alpha_0[j]
  if (j == 0) aslot[1] = a;
  float x0 = xb[1 * Tc + j];          // emit prefetch, 2 steps deep
  float x1 = xb[2 * Tc + j];
  __syncthreads();                    // publishes aslot + s_score
  float m = aslot[1];                 // shift for first step = alpha_0[0] (exact)

  for (int t = 1; t < Lc; ++t) {
    const int c = t & 1;
    int tpre = (t + 2 < Lc) ? (t + 2) : (Lc - 1);
    float x2 = xb[tpre * Tc + j];     // stays in flight across raw barriers
    const float s = m;                // shift used THIS step (exact lse shift)
    float pj = __expf(a - s);
    pbuf[c][j] = pj;
    if (j == 0) aslot[c] = a;         // publish alpha_{t-1}[0] for next step's shift
    bar_lgkm();
    m = aslot[c];

    const float4* P4 = (const float4*)pbuf[c];
    float acc0 = 0.f, acc1 = 0.f, acc2 = 0.f, acc3 = 0.f;
#define BLK(K, EV, ACC) { float4 pv = P4[K]; \
    ACC = fmaf(EV.x, pv.x, ACC); ACC = fmaf(EV.y, pv.y, ACC); \
    ACC = fmaf(EV.z, pv.z, ACC); ACC = fmaf(EV.w, pv.w, ACC); }
    BLK(0,  e0,  acc0) BLK(1,  e1,  acc1) BLK(2,  e2,  acc2) BLK(3,  e3,  acc3)
    BLK(4,  e4,  acc0) BLK(5,  e5,  acc1) BLK(6,  e6,  acc2) BLK(7,  e7,  acc3)
    BLK(8,  e8,  acc0) BLK(9,  e9,  acc1) BLK(10, e10, acc2) BLK(11, e11, acc3)
    BLK(12, e12, acc0) BLK(13, e13, acc1) BLK(14, e14, acc2) BLK(15, e15, acc3)
    BLK(16, e16, acc0) BLK(17, e17, acc1) BLK(18, e18, acc2) BLK(19, e19, acc3)
    BLK(20, e20, acc0) BLK(21, e21, acc1) BLK(22, e22, acc2) BLK(23, e23, acc3)
    BLK(24, e24, acc0) BLK(25, e25, acc1) BLK(26, e26, acc2) BLK(27, e27, acc3)
    BLK(28, e28, acc0) BLK(29, e29, acc1) BLK(30, e30, acc2) BLK(31, e31, acc3)
#undef BLK
    float acc = (acc0 + acc1) + (acc2 + acc3);
    float na = x0 + s + __logf(acc);
    a = mask_s[t] ? na : a;           // mask blend (mask in {0,1})
    x0 = x1; x1 = x2;
  }

  // ---- log_denominator = logsumexp_j(alpha + end) ----
  float v = a + endT[j];
  float wm = v;
#pragma unroll
  for (int off = 32; off; off >>= 1) wm = fmaxf(wm, __shfl_xor(wm, off));
  if (lane == 0) sred[wid] = wm;
  __syncthreads();
  float M = fmaxf(sred[0], sred[1]);
  float e = __expf(v - M);
  float wsum = e;
#pragma unroll
  for (int off = 32; off; off >>= 1) wsum += __shfl_xor(wsum, off);
  if (lane == 0) sred[2 + wid] = wsum;
  __syncthreads();
  if (j == 0) {
    float ld = M + __logf(sred[2] + sred[3]);
    diff_out[b] = ld - s_score;
    msum_out[b] = (float)msum;
  }
}

__global__ __launch_bounds__(512)
void crf_final(const float* __restrict__ diff, const float* __restrict__ msum,
               float* __restrict__ out)
{
  __shared__ float sd[512];
  __shared__ float sm[512];
  int t = threadIdx.x;
  sd[t] = diff[t];
  sm[t] = msum[t];
  __syncthreads();
  for (int s = 256; s > 0; s >>= 1) {
    if (t < s) { sd[t] += sd[t + s]; sm[t] += sm[t + s]; }
    __syncthreads();
  }
  if (t == 0) out[0] = sd[0] / sm[0];
}

extern "C" void kernel_launch(void* const* d_in, const int* in_sizes, int n_in,
                              void* d_out, int out_size, void* d_ws, size_t ws_size,
                              hipStream_t stream) {
  const float* x      = (const float*)d_in[0];
  const float* trans  = (const float*)d_in[1];
  const float* startT = (const float*)d_in[2];
  const float* endT   = (const float*)d_in[3];
  const int*   labels = (const int*)d_in[4];
  const int*   mask   = (const int*)d_in[5];
  float* out = (float*)d_out;
  float* ws  = (float*)d_ws;
  float* diff = ws;        // [512]
  float* msum = ws + Bc;   // [512]

  crf_forward<<<dim3(Bc), dim3(128), 0, stream>>>(
      x, trans, startT, endT, labels, mask, diff, msum);
  crf_final<<<dim3(1), dim3(512), 0, stream>>>(diff, msum, out);
}

// Round 4
// 406.440 us; speedup vs baseline: 1.4759x; 1.4678x over previous
//
#include <hip/hip_runtime.h>

#define Bc 512
#define Lc 512
#define Tc 128

// raw barrier: drain LDS ops, do NOT drain vmcnt (global prefetches stay in flight)
__device__ __forceinline__ void bar_lgkm() {
  asm volatile("s_waitcnt lgkmcnt(0)\n\ts_barrier" ::: "memory");
}

__global__ __launch_bounds__(256) __attribute__((amdgpu_waves_per_eu(1, 4)))
void crf_forward(const float* __restrict__ x,      // [B,L,T]
                 const float* __restrict__ trans,  // [T,T]
                 const float* __restrict__ startT, // [T]
                 const float* __restrict__ endT,   // [T]
                 const int*   __restrict__ labels, // [B,L]
                 const int*   __restrict__ mask,   // [B,L]
                 float* __restrict__ diff_out,     // [B] logZ - score
                 float* __restrict__ msum_out)     // [B] per-batch mask sum
{
  __shared__ __align__(16) float pbuf[2][Tc];
  __shared__ float part[2][2][Tc];    // [buf][quarter][col]
  __shared__ float aslot[2];
  __shared__ float sred[256];
  __shared__ int   mask_s[Lc];
  __shared__ float s_score;
  __shared__ int   s_msum;

  const int tid  = threadIdx.x;       // 0..255
  const int j    = tid & 127;         // tag column
  const int q    = tid >> 7;          // K-half: rows [64q, 64q+64)
  const int w    = tid >> 6;          // wave id 0..3
  const int lane = tid & 63;
  const int b    = blockIdx.x;        // batch
  const float* xb = x + (size_t)b * (Lc * Tc);
  const int* lb = labels + b * Lc;
  const int* mk = mask   + b * Lc;

  // ---- stage mask row into LDS ----
  for (int t = tid; t < Lc; t += 256) mask_s[t] = mk[t];
  __syncthreads();

  // ---- mask sum ----
  int mpart = 0;
  for (int t = tid; t < Lc; t += 256) mpart += mask_s[t];
  sred[tid] = (float)mpart;
  __syncthreads();
#pragma unroll
  for (int s = 128; s > 0; s >>= 1) {
    if (tid < s) sred[tid] += sred[tid + s];
    __syncthreads();
  }
  if (tid == 0) s_msum = (int)sred[0];
  __syncthreads();
  const int msum = s_msum;

  // ---- gold-path score ----
  float spart = 0.f;
  for (int t = tid; t < Lc - 1; t += 256) {
    int l0 = lb[t], l1 = lb[t + 1];
    float m0 = (float)mask_s[t], m1 = (float)mask_s[t + 1];
    spart += trans[l0 * Tc + l1] * m1 + xb[t * Tc + l0] * m0;
  }
  __syncthreads();
  sred[tid] = spart;
  __syncthreads();
#pragma unroll
  for (int s = 128; s > 0; s >>= 1) {
    if (tid < s) sred[tid] += sred[tid + s];
    __syncthreads();
  }
  if (tid == 0) {
    int last_idx = msum - 1;
    int lt = lb[last_idx];
    s_score = sred[0] + startT[lb[0]] + endT[lt]
            + xb[(Lc - 1) * Tc + lt] * (float)mask_s[Lc - 1];
  }

  // ---- E half-column in registers: 64 floats/thread, rows [64q, 64q+64) of col j.
  //      Pins block rematerialization; 64 regs fits the allocator's budget.
  const float* tcol = trans + (size_t)(64 * q) * Tc + j;
#define LOADE(K) float4 e##K; \
  e##K.x = __expf(tcol[(4*K+0)*Tc]); \
  e##K.y = __expf(tcol[(4*K+1)*Tc]); \
  e##K.z = __expf(tcol[(4*K+2)*Tc]); \
  e##K.w = __expf(tcol[(4*K+3)*Tc]); \
  asm volatile("" : "+v"(e##K.x), "+v"(e##K.y), "+v"(e##K.z), "+v"(e##K.w));
  LOADE(0)  LOADE(1)  LOADE(2)  LOADE(3)
  LOADE(4)  LOADE(5)  LOADE(6)  LOADE(7)
  LOADE(8)  LOADE(9)  LOADE(10) LOADE(11)
  LOADE(12) LOADE(13) LOADE(14) LOADE(15)
#undef LOADE

  // ---- forward recurrence (alpha replicated across the two K-halves) ----
  float a = startT[j] + xb[j];        // alpha_0[j]
  if (tid == 0) aslot[1] = a;
  float x0 = xb[1 * Tc + j];          // emit prefetch, 2 steps deep
  float x1 = xb[2 * Tc + j];
  __syncthreads();                    // publishes aslot + s_score
  float m = aslot[1];                 // shift for first step = alpha_0[0] (exact)

  for (int t = 1; t < Lc; ++t) {
    const int c = t & 1;
    int tpre = (t + 2 < Lc) ? (t + 2) : (Lc - 1);
    float x2 = xb[tpre * Tc + j];     // stays in flight across raw barriers
    const float s = m;                // shift used THIS step (stale-but-exact lse shift)
    if (q == 0) {                     // wave-uniform branch
      pbuf[c][j] = __expf(a - s);
    }
    if (tid == 0) aslot[c] = a;       // publish alpha_{t-1}[0] for next step's shift
    bar_lgkm();
    m = aslot[c];

    const float4* P4 = ((const float4*)pbuf[c]) + (q << 4);
    float acc0 = 0.f, acc1 = 0.f, acc2 = 0.f, acc3 = 0.f;
#define BLK(K, EV, ACC) { float4 pv = P4[K]; \
    ACC = fmaf(EV.x, pv.x, ACC); ACC = fmaf(EV.y, pv.y, ACC); \
    ACC = fmaf(EV.z, pv.z, ACC); ACC = fmaf(EV.w, pv.w, ACC); }
    BLK(0,  e0,  acc0) BLK(1,  e1,  acc1) BLK(2,  e2,  acc2) BLK(3,  e3,  acc3)
    BLK(4,  e4,  acc0) BLK(5,  e5,  acc1) BLK(6,  e6,  acc2) BLK(7,  e7,  acc3)
    BLK(8,  e8,  acc0) BLK(9,  e9,  acc1) BLK(10, e10, acc2) BLK(11, e11, acc3)
    BLK(12, e12, acc0) BLK(13, e13, acc1) BLK(14, e14, acc2) BLK(15, e15, acc3)
#undef BLK
    part[c][q][j] = (acc0 + acc1) + (acc2 + acc3);
    bar_lgkm();

    float tot = part[c][0][j] + part[c][1][j];
    float na = x0 + s + __logf(tot);
    a = mask_s[t] ? na : a;           // mask blend (mask in {0,1})
    x0 = x1; x1 = x2;
  }

  // ---- log_denominator = logsumexp_j(alpha + end); q-halves redundant ----
  float v = a + endT[j];
  float wm = v;
#pragma unroll
  for (int off = 32; off; off >>= 1) wm = fmaxf(wm, __shfl_xor(wm, off));
  if (lane == 0 && w < 2) sred[w] = wm;
  __syncthreads();
  float M = fmaxf(sred[0], sred[1]);
  float e = __expf(v - M);
  float wsum = e;
#pragma unroll
  for (int off = 32; off; off >>= 1) wsum += __shfl_xor(wsum, off);
  if (lane == 0 && w < 2) sred[2 + w] = wsum;
  __syncthreads();
  if (tid == 0) {
    float ld = M + __logf(sred[2] + sred[3]);
    diff_out[b] = ld - s_score;
    msum_out[b] = (float)msum;
  }
}

__global__ __launch_bounds__(512)
void crf_final(const float* __restrict__ diff, const float* __restrict__ msum,
               float* __restrict__ out)
{
  __shared__ float sd[512];
  __shared__ float sm[512];
  int t = threadIdx.x;
  sd[t] = diff[t];
  sm[t] = msum[t];
  __syncthreads();
  for (int s = 256; s > 0; s >>= 1) {
    if (t < s) { sd[t] += sd[t + s]; sm[t] += sm[t + s]; }
    __syncthreads();
  }
  if (t == 0) out[0] = sd[0] / sm[0];
}

extern "C" void kernel_launch(void* const* d_in, const int* in_sizes, int n_in,
                              void* d_out, int out_size, void* d_ws, size_t ws_size,
                              hipStream_t stream) {
  const float* x      = (const float*)d_in[0];
  const float* trans  = (const float*)d_in[1];
  const float* startT = (const float*)d_in[2];
  const float* endT   = (const float*)d_in[3];
  const int*   labels = (const int*)d_in[4];
  const int*   mask   = (const int*)d_in[5];
  float* out = (float*)d_out;
  float* ws  = (float*)d_ws;
  float* diff = ws;        // [512]
  float* msum = ws + Bc;   // [512]

  crf_forward<<<dim3(Bc), dim3(256), 0, stream>>>(
      x, trans, startT, endT, labels, mask, diff, msum);
  crf_final<<<dim3(1), dim3(512), 0, stream>>>(diff, msum, out);
}

// Round 5
// 331.805 us; speedup vs baseline: 1.8078x; 1.2249x over previous
//
#include <hip/hip_runtime.h>
#include <hip/hip_bf16.h>

#define Bc 512
#define Lc 512
#define Tc 128
#define GB 16   // batches per block
#define NW 8    // waves per block

typedef __attribute__((ext_vector_type(8))) short bf16x8;
typedef __attribute__((ext_vector_type(4))) float f32x4;

// raw barrier: drain LDS ops only; global prefetches stay in flight
__device__ __forceinline__ void bar_lgkm() {
  asm volatile("s_waitcnt lgkmcnt(0)\n\ts_barrier" ::: "memory");
}

__device__ __forceinline__ short f2bf(float f) {
  __hip_bfloat16 h = __float2bfloat16(f);
  unsigned short us;
  __builtin_memcpy(&us, &h, 2);
  return (short)us;
}

// LDS column swizzle (element units, applied to col index, keyed by row):
// reads 2-way (free), writes conflict-free (derivation in round-5 notes)
__device__ __forceinline__ int swz(int row) {
  return ((row & 7) << 3) ^ ((row & 12) << 2);
}

__global__ __launch_bounds__(512, 2)
void crf_forward(const float* __restrict__ x,      // [B,L,T]
                 const float* __restrict__ trans,  // [T,T]
                 const float* __restrict__ startT, // [T]
                 const float* __restrict__ endT,   // [T]
                 const int*   __restrict__ labels, // [B,L]
                 const int*   __restrict__ mask,   // [B,L]
                 float* __restrict__ diff_out,     // [B]
                 float* __restrict__ msum_out)     // [B]
{
  __shared__ __align__(16) unsigned short Pl[GB][Tc]; // A-tile (bf16 bits), swizzled
  __shared__ __align__(16) float r_s[GB];
  __shared__ __align__(16) float c_s[GB];
  __shared__ float score_s[GB];
  __shared__ float msum_s[GB];
  __shared__ float red[GB][NW];
  __shared__ unsigned char m8[GB][Lc];

  const int tid  = threadIdx.x;
  const int lane = tid & 63;
  const int w    = tid >> 6;        // wave 0..7 owns j-tile [16w,16w+16)
  const int crow = lane & 15;
  const int khi  = lane >> 4;       // 0..3
  const int bg0  = blockIdx.x * GB;
  const int jloc = 16 * w + crow;   // 0..127

  // ---- stage mask bytes into LDS ----
  for (int i = tid; i < GB * Lc; i += 512) {
    m8[i >> 9][i & (Lc - 1)] =
        (unsigned char)mask[(size_t)(bg0 + (i >> 9)) * Lc + (i & (Lc - 1))];
  }

  // ---- gold-path score + msum: wave w handles local batches 2w, 2w+1 ----
  for (int bb = 2 * w; bb < 2 * w + 2; ++bb) {
    const int bglob = bg0 + bb;
    const int* lbp = labels + (size_t)bglob * Lc;
    const int* mkp = mask + (size_t)bglob * Lc;
    const float* xrow = x + (size_t)bglob * Lc * Tc;
    float sp = 0.f, msp = 0.f;
    for (int t = lane; t < Lc; t += 64) {
      int l0 = lbp[t];
      int m0 = mkp[t];
      msp += (float)m0;
      if (t < Lc - 1) {
        int l1 = lbp[t + 1];
        float m1 = (float)mkp[t + 1];
        sp += trans[l0 * Tc + l1] * m1 + xrow[(size_t)t * Tc + l0] * (float)m0;
      }
    }
#pragma unroll
    for (int off = 32; off; off >>= 1) {
      sp += __shfl_xor(sp, off);
      msp += __shfl_xor(msp, off);
    }
    if (lane == 0) {
      int last_idx = (int)msp - 1;
      int lt = lbp[last_idx];
      score_s[bb] = sp + startT[lbp[0]] + endT[lt]
                  + xrow[(size_t)(Lc - 1) * Tc + lt] * (float)mkp[Lc - 1];
      msum_s[bb] = msp;
    }
  }

  // ---- E fragments (B-operand), 16 VGPRs total: wave w's 16-j slice ----
  // B layout (16x16x32): lane holds B[k = 32c + 8*khi + e][col = crow]
  bf16x8 Bf0, Bf1, Bf2, Bf3;
  {
    const float* tp_ = trans + jloc;
#pragma unroll
    for (int e = 0; e < 8; ++e) Bf0[e] = f2bf(__expf(tp_[(8 * khi + e) * Tc]));
#pragma unroll
    for (int e = 0; e < 8; ++e) Bf1[e] = f2bf(__expf(tp_[(32 + 8 * khi + e) * Tc]));
#pragma unroll
    for (int e = 0; e < 8; ++e) Bf2[e] = f2bf(__expf(tp_[(64 + 8 * khi + e) * Tc]));
#pragma unroll
    for (int e = 0; e < 8; ++e) Bf3[e] = f2bf(__expf(tp_[(96 + 8 * khi + e) * Tc]));
  }

  // ---- per-lane constant pointers ----
  // C/D layout: batch b = 4*khi + e (row), col j = crow  [verified m89/m91]
  const int b0 = 4 * khi + 0, b1 = 4 * khi + 1, b2 = 4 * khi + 2, b3 = 4 * khi + 3;
  // A-frag reads: A[row = crow][k = 32c + 8*khi + e]
  const bf16x8* rp0 = (const bf16x8*)&Pl[crow][(0  + 8 * khi) ^ swz(crow)];
  const bf16x8* rp1 = (const bf16x8*)&Pl[crow][(32 + 8 * khi) ^ swz(crow)];
  const bf16x8* rp2 = (const bf16x8*)&Pl[crow][(64 + 8 * khi) ^ swz(crow)];
  const bf16x8* rp3 = (const bf16x8*)&Pl[crow][(96 + 8 * khi) ^ swz(crow)];
  __hip_bfloat16* wp0 = (__hip_bfloat16*)&Pl[b0][jloc ^ swz(b0)];
  __hip_bfloat16* wp1 = (__hip_bfloat16*)&Pl[b1][jloc ^ swz(b1)];
  __hip_bfloat16* wp2 = (__hip_bfloat16*)&Pl[b2][jloc ^ swz(b2)];
  __hip_bfloat16* wp3 = (__hip_bfloat16*)&Pl[b3][jloc ^ swz(b3)];
  const unsigned char* mq0 = &m8[b0][0];
  const unsigned char* mq1 = &m8[b1][0];
  const unsigned char* mq2 = &m8[b2][0];
  const unsigned char* mq3 = &m8[b3][0];
  const float* xp0 = x + (size_t)(bg0 + b0) * Lc * Tc + jloc;
  const float* xp1 = x + (size_t)(bg0 + b1) * Lc * Tc + jloc;
  const float* xp2 = x + (size_t)(bg0 + b2) * Lc * Tc + jloc;
  const float* xp3 = x + (size_t)(bg0 + b3) * Lc * Tc + jloc;

  float c0 = 0.f, c1 = 0.f, c2 = 0.f, c3 = 0.f;
  __syncthreads();  // m8 staged

  // ---- init: alpha_0 = start + x_0; c_b = alpha_0[b][0]; P = exp(alpha0 - c) ----
  float st_j = startT[jloc];
  float a00 = st_j + xp0[0];
  float a01 = st_j + xp1[0];
  float a02 = st_j + xp2[0];
  float a03 = st_j + xp3[0];
  if (w == 0 && crow == 0) {
    f32x4 cv = {a00, a01, a02, a03};
    *(f32x4*)&r_s[khi << 2] = cv;
    c0 = a00; c1 = a01; c2 = a02; c3 = a03;
  }
  __syncthreads();
  f32x4 cb = *(const f32x4*)&r_s[khi << 2];
  float Ao0 = __expf(a00 - cb.x);
  float Ao1 = __expf(a01 - cb.y);
  float Ao2 = __expf(a02 - cb.z);
  float Ao3 = __expf(a03 - cb.w);
  *wp0 = __float2bfloat16(Ao0);
  *wp1 = __float2bfloat16(Ao1);
  *wp2 = __float2bfloat16(Ao2);
  *wp3 = __float2bfloat16(Ao3);
  // x prefetch: set A for t=1, set B for t=2
  float xA0 = xp0[(size_t)1 * Tc], xA1 = xp1[(size_t)1 * Tc];
  float xA2 = xp2[(size_t)1 * Tc], xA3 = xp3[(size_t)1 * Tc];
  float xB0 = xp0[(size_t)2 * Tc], xB1 = xp1[(size_t)2 * Tc];
  float xB2 = xp2[(size_t)2 * Tc], xB3 = xp3[(size_t)2 * Tc];
  __syncthreads();  // P-tile ready

#define STEP(T, XA0, XA1, XA2, XA3) do {                                      \
    bf16x8 Af0 = *rp0, Af1 = *rp1, Af2 = *rp2, Af3 = *rp3;                    \
    float ex0 = __expf(XA0), ex1 = __expf(XA1);                               \
    float ex2 = __expf(XA2), ex3 = __expf(XA3);                               \
    int mv0 = mq0[T], mv1 = mq1[T], mv2 = mq2[T], mv3 = mq3[T];               \
    f32x4 Cr = {0.f, 0.f, 0.f, 0.f};                                          \
    Cr = __builtin_amdgcn_mfma_f32_16x16x32_bf16(Af0, Bf0, Cr, 0, 0, 0);      \
    Cr = __builtin_amdgcn_mfma_f32_16x16x32_bf16(Af1, Bf1, Cr, 0, 0, 0);      \
    Cr = __builtin_amdgcn_mfma_f32_16x16x32_bf16(Af2, Bf2, Cr, 0, 0, 0);      \
    Cr = __builtin_amdgcn_mfma_f32_16x16x32_bf16(Af3, Bf3, Cr, 0, 0, 0);      \
    int tp = (T) + 2 < Lc ? (T) + 2 : Lc - 1;                                 \
    XA0 = xp0[(size_t)tp * Tc]; XA1 = xp1[(size_t)tp * Tc];                   \
    XA2 = xp2[(size_t)tp * Tc]; XA3 = xp3[(size_t)tp * Tc];                   \
    if (w == 0 && crow == 0) {                                                \
      f32x4 rv;                                                               \
      rv.x = __builtin_amdgcn_rcpf(Cr.x);                                     \
      rv.y = __builtin_amdgcn_rcpf(Cr.y);                                     \
      rv.z = __builtin_amdgcn_rcpf(Cr.z);                                     \
      rv.w = __builtin_amdgcn_rcpf(Cr.w);                                     \
      *(f32x4*)&r_s[khi << 2] = rv;                                           \
      c0 += mv0 ? __logf(Cr.x) : 0.f;                                         \
      c1 += mv1 ? __logf(Cr.y) : 0.f;                                         \
      c2 += mv2 ? __logf(Cr.z) : 0.f;                                         \
      c3 += mv3 ? __logf(Cr.w) : 0.f;                                         \
    }                                                                         \
    bar_lgkm();                                                               \
    f32x4 rr = *(const f32x4*)&r_s[khi << 2];                                 \
    Ao0 = mv0 ? Cr.x * rr.x * ex0 : Ao0;                                      \
    Ao1 = mv1 ? Cr.y * rr.y * ex1 : Ao1;                                      \
    Ao2 = mv2 ? Cr.z * rr.z * ex2 : Ao2;                                      \
    Ao3 = mv3 ? Cr.w * rr.w * ex3 : Ao3;                                      \
    *wp0 = __float2bfloat16(Ao0); *wp1 = __float2bfloat16(Ao1);               \
    *wp2 = __float2bfloat16(Ao2); *wp3 = __float2bfloat16(Ao3);               \
    bar_lgkm();                                                               \
  } while (0)

  for (int t = 1; t < Lc; t += 2) {
    STEP(t, xA0, xA1, xA2, xA3);
    if (t + 1 < Lc) { STEP(t + 1, xB0, xB1, xB2, xB3); }
  }
#undef STEP

  // ---- logZ_b = c_b + log(sum_j Abar[b][j] * exp(end[j])) ----
  float eex = __expf(endT[jloc]);
  float v0 = Ao0 * eex, v1 = Ao1 * eex, v2 = Ao2 * eex, v3 = Ao3 * eex;
#pragma unroll
  for (int off = 1; off < 16; off <<= 1) {
    v0 += __shfl_xor(v0, off);
    v1 += __shfl_xor(v1, off);
    v2 += __shfl_xor(v2, off);
    v3 += __shfl_xor(v3, off);
  }
  if (crow == 0) {
    red[4 * khi + 0][w] = v0;
    red[4 * khi + 1][w] = v1;
    red[4 * khi + 2][w] = v2;
    red[4 * khi + 3][w] = v3;
    if (w == 0) {
      f32x4 cv = {c0, c1, c2, c3};
      *(f32x4*)&c_s[khi << 2] = cv;
    }
  }
  __syncthreads();
  if (tid < GB) {
    float tot = 0.f;
#pragma unroll
    for (int ww = 0; ww < NW; ++ww) tot += red[tid][ww];
    float logZ = c_s[tid] + __logf(tot);
    diff_out[bg0 + tid] = logZ - score_s[tid];
    msum_out[bg0 + tid] = msum_s[tid];
  }
}

__global__ __launch_bounds__(512)
void crf_final(const float* __restrict__ diff, const float* __restrict__ msum,
               float* __restrict__ out)
{
  __shared__ float sd[512];
  __shared__ float sm[512];
  int t = threadIdx.x;
  sd[t] = diff[t];
  sm[t] = msum[t];
  __syncthreads();
  for (int s = 256; s > 0; s >>= 1) {
    if (t < s) { sd[t] += sd[t + s]; sm[t] += sm[t + s]; }
    __syncthreads();
  }
  if (t == 0) out[0] = sd[0] / sm[0];
}

extern "C" void kernel_launch(void* const* d_in, const int* in_sizes, int n_in,
                              void* d_out, int out_size, void* d_ws, size_t ws_size,
                              hipStream_t stream) {
  const float* x      = (const float*)d_in[0];
  const float* trans  = (const float*)d_in[1];
  const float* startT = (const float*)d_in[2];
  const float* endT   = (const float*)d_in[3];
  const int*   labels = (const int*)d_in[4];
  const int*   mask   = (const int*)d_in[5];
  float* out = (float*)d_out;
  float* ws  = (float*)d_ws;
  float* diff = ws;        // [512]
  float* msum = ws + Bc;   // [512]

  crf_forward<<<dim3(Bc / GB), dim3(512), 0, stream>>>(
      x, trans, startT, endT, labels, mask, diff, msum);
  crf_final<<<dim3(1), dim3(512), 0, stream>>>(diff, msum, out);
}

// Round 6
// 261.484 us; speedup vs baseline: 2.2940x; 1.2689x over previous
//
#include <hip/hip_runtime.h>
#include <hip/hip_bf16.h>

#define Bc 512
#define Lc 512
#define Tc 128
#define GB 16     // batches per block
#define NW 8      // waves per block
#define PSTR 136  // padded P row stride in bf16 elems (272B = 17*16B: aligned, bank-balanced)
#define PBUF (GB * PSTR)

typedef __attribute__((ext_vector_type(8))) short bf16x8;
typedef __attribute__((ext_vector_type(4))) float f32x4;

// raw barrier: drain LDS ops only; global prefetches stay in flight
__device__ __forceinline__ void bar_lgkm() {
  asm volatile("s_waitcnt lgkmcnt(0)\n\ts_barrier" ::: "memory");
}

__device__ __forceinline__ short f2bf(float f) {
  __hip_bfloat16 h = __float2bfloat16(f);
  unsigned short us;
  __builtin_memcpy(&us, &h, 2);
  return (short)us;
}

__global__ __launch_bounds__(512, 1)
void crf_forward(const float* __restrict__ x,      // [B,L,T]
                 const float* __restrict__ trans,  // [T,T]
                 const float* __restrict__ startT, // [T]
                 const float* __restrict__ endT,   // [T]
                 const int*   __restrict__ labels, // [B,L]
                 const int*   __restrict__ mask,   // [B,L]
                 float* __restrict__ diff_out,     // [B]
                 float* __restrict__ msum_out)     // [B]
{
  __shared__ __align__(16) unsigned short Pl[2 * PBUF]; // double-buffered A-tile, padded
  __shared__ __align__(16) float r_s[2][GB];            // double-buffered rescale bcast
  __shared__ __align__(16) unsigned char mT[Lc][GB];    // transposed mask bytes [t][b]
  __shared__ __align__(16) float c_s[GB];
  __shared__ float score_s[GB];
  __shared__ float msum_s[GB];
  __shared__ float red[GB][NW];

  const int tid  = threadIdx.x;
  const int lane = tid & 63;
  const int w    = tid >> 6;        // wave 0..7 owns j-tile [16w,16w+16)
  const int crow = lane & 15;
  const int khi  = lane >> 4;       // 0..3
  const int bg0  = blockIdx.x * GB;
  const int jloc = 16 * w + crow;   // 0..127

  // ---- stage transposed mask bytes (coalesced over t) ----
  for (int i = tid; i < GB * Lc; i += 512) {
    int bb = i >> 9;                // 0..15
    int t  = i & (Lc - 1);
    mT[t][bb] = (unsigned char)mask[(size_t)(bg0 + bb) * Lc + t];
  }

  // ---- gold-path score + msum: wave w handles local batches 2w, 2w+1 ----
  for (int bb = 2 * w; bb < 2 * w + 2; ++bb) {
    const int bglob = bg0 + bb;
    const int* lbp = labels + (size_t)bglob * Lc;
    const int* mkp = mask + (size_t)bglob * Lc;
    const float* xrow = x + (size_t)bglob * Lc * Tc;
    float sp = 0.f, msp = 0.f;
    for (int t = lane; t < Lc; t += 64) {
      int l0 = lbp[t];
      int m0 = mkp[t];
      msp += (float)m0;
      if (t < Lc - 1) {
        int l1 = lbp[t + 1];
        float m1 = (float)mkp[t + 1];
        sp += trans[l0 * Tc + l1] * m1 + xrow[(size_t)t * Tc + l0] * (float)m0;
      }
    }
#pragma unroll
    for (int off = 32; off; off >>= 1) {
      sp += __shfl_xor(sp, off);
      msp += __shfl_xor(msp, off);
    }
    if (lane == 0) {
      int last_idx = (int)msp - 1;
      int lt = lbp[last_idx];
      score_s[bb] = sp + startT[lbp[0]] + endT[lt]
                  + xrow[(size_t)(Lc - 1) * Tc + lt] * (float)mkp[Lc - 1];
      msum_s[bb] = msp;
    }
  }

  // ---- E fragments (B-operand): wave w's 16-j slice; 16 VGPRs ----
  bf16x8 Bf0, Bf1, Bf2, Bf3;
  {
    const float* tp_ = trans + jloc;
#pragma unroll
    for (int e = 0; e < 8; ++e) Bf0[e] = f2bf(__expf(tp_[(8 * khi + e) * Tc]));
#pragma unroll
    for (int e = 0; e < 8; ++e) Bf1[e] = f2bf(__expf(tp_[(32 + 8 * khi + e) * Tc]));
#pragma unroll
    for (int e = 0; e < 8; ++e) Bf2[e] = f2bf(__expf(tp_[(64 + 8 * khi + e) * Tc]));
#pragma unroll
    for (int e = 0; e < 8; ++e) Bf3[e] = f2bf(__expf(tp_[(96 + 8 * khi + e) * Tc]));
  }

  // ---- per-lane constant offsets / pointers ----
  // C/D layout: row b = 4*khi + r, col j = crow (verified round 5)
  const int aoff = crow * PSTR + 8 * khi;       // A-frag elem base: A[row=crow][k=8khi]
  const int woff = (4 * khi) * PSTR + jloc;     // write elem base: row 4khi, col jloc
  unsigned short* PF = &Pl[0];
  const float* xp0 = x + (size_t)(bg0 + 4 * khi + 0) * Lc * Tc + jloc;
  const float* xp1 = x + (size_t)(bg0 + 4 * khi + 1) * Lc * Tc + jloc;
  const float* xp2 = x + (size_t)(bg0 + 4 * khi + 2) * Lc * Tc + jloc;
  const float* xp3 = x + (size_t)(bg0 + 4 * khi + 3) * Lc * Tc + jloc;

  const bool rlane = (w == 0) && (crow == 0);   // 4 lanes own rescale + c for all 16 b

  __syncthreads();  // mT staged, score_s/msum_s ready

  // ---- init: alpha_0 = start + x_0; exact renorm by alpha_0[b][0] ----
  float st_j = startT[jloc];
  float a00 = st_j + xp0[0];
  float a01 = st_j + xp1[0];
  float a02 = st_j + xp2[0];
  float a03 = st_j + xp3[0];
  if (rlane) {                      // these lanes have jloc==0
    f32x4 cv = {a00, a01, a02, a03};
    *(f32x4*)&r_s[1][khi << 2] = cv;
  }
  __syncthreads();
  f32x4 cb = *(const f32x4*)&r_s[1][khi << 2];
  float Ao0 = __expf(a00 - cb.x);
  float Ao1 = __expf(a01 - cb.y);
  float Ao2 = __expf(a02 - cb.z);
  float Ao3 = __expf(a03 - cb.w);
  PF[PBUF + woff + 0 * PSTR] = (unsigned short)f2bf(Ao0);
  PF[PBUF + woff + 1 * PSTR] = (unsigned short)f2bf(Ao1);
  PF[PBUF + woff + 2 * PSTR] = (unsigned short)f2bf(Ao2);
  PF[PBUF + woff + 3 * PSTR] = (unsigned short)f2bf(Ao3);
  float c0 = 0.f, c1 = 0.f, c2 = 0.f, c3 = 0.f;
  f32x4 lr = {0.f, 0.f, 0.f, 0.f};  // log of the S[0] that the CURRENT r came from
  if (rlane) { c0 = a00; c1 = a01; c2 = a02; c3 = a03; }
  __syncthreads();                  // cb reads done; safe to overwrite r_s[1]
  if (rlane) {                      // Abar_0 is exactly normalized -> r = 1
    f32x4 one = {1.f, 1.f, 1.f, 1.f};
    *(f32x4*)&r_s[1][khi << 2] = one;
  }
  // x prefetch, depth 2
  float xA0 = xp0[(size_t)1 * Tc], xA1 = xp1[(size_t)1 * Tc];
  float xA2 = xp2[(size_t)1 * Tc], xA3 = xp3[(size_t)1 * Tc];
  float xB0 = xp0[(size_t)2 * Tc], xB1 = xp1[(size_t)2 * Tc];
  float xB2 = xp2[(size_t)2 * Tc], xB3 = xp3[(size_t)2 * Tc];
  __syncthreads();                  // P[1], r_s[1] visible

  // Step t: S_t = Abar_{t-1} @ E (f32 acc); Abar_t = S_t * r_stale * exp(x_t) (masked);
  // c += mask ? log(S_prev[0]) : 0 at USE time; r,lr refreshed every step (valid:
  // S is a function of the current state whether or not alpha updated).
#define STEP(T, RB, WB, XA0, XA1, XA2, XA3) do {                               \
    bf16x8 Af0 = *(const bf16x8*)&PF[(RB) * PBUF + aoff +  0];                 \
    bf16x8 Af1 = *(const bf16x8*)&PF[(RB) * PBUF + aoff + 32];                 \
    bf16x8 Af2 = *(const bf16x8*)&PF[(RB) * PBUF + aoff + 64];                 \
    bf16x8 Af3 = *(const bf16x8*)&PF[(RB) * PBUF + aoff + 96];                 \
    f32x4 rr = *(const f32x4*)&r_s[RB][khi << 2];                              \
    unsigned mw = *(const unsigned*)&mT[T][khi << 2];                          \
    float ex0 = __expf(XA0), ex1 = __expf(XA1);                                \
    float ex2 = __expf(XA2), ex3 = __expf(XA3);                                \
    f32x4 Ca = {0.f, 0.f, 0.f, 0.f};                                           \
    f32x4 Cb2 = {0.f, 0.f, 0.f, 0.f};                                          \
    Ca  = __builtin_amdgcn_mfma_f32_16x16x32_bf16(Af0, Bf0, Ca, 0, 0, 0);      \
    Ca  = __builtin_amdgcn_mfma_f32_16x16x32_bf16(Af1, Bf1, Ca, 0, 0, 0);      \
    Cb2 = __builtin_amdgcn_mfma_f32_16x16x32_bf16(Af2, Bf2, Cb2, 0, 0, 0);     \
    Cb2 = __builtin_amdgcn_mfma_f32_16x16x32_bf16(Af3, Bf3, Cb2, 0, 0, 0);     \
    f32x4 Cr = Ca + Cb2;                                                       \
    int tp = (T) + 2 < Lc ? (T) + 2 : Lc - 1;                                  \
    XA0 = xp0[(size_t)tp * Tc]; XA1 = xp1[(size_t)tp * Tc];                    \
    XA2 = xp2[(size_t)tp * Tc]; XA3 = xp3[(size_t)tp * Tc];                    \
    float v0 = Cr.x * rr.x * ex0;                                              \
    float v1 = Cr.y * rr.y * ex1;                                              \
    float v2 = Cr.z * rr.z * ex2;                                              \
    float v3 = Cr.w * rr.w * ex3;                                              \
    Ao0 = (mw & 0x1u)       ? v0 : Ao0;                                        \
    Ao1 = (mw & 0x100u)     ? v1 : Ao1;                                        \
    Ao2 = (mw & 0x10000u)   ? v2 : Ao2;                                        \
    Ao3 = (mw & 0x1000000u) ? v3 : Ao3;                                        \
    PF[(WB) * PBUF + woff + 0 * PSTR] = (unsigned short)f2bf(Ao0);             \
    PF[(WB) * PBUF + woff + 1 * PSTR] = (unsigned short)f2bf(Ao1);             \
    PF[(WB) * PBUF + woff + 2 * PSTR] = (unsigned short)f2bf(Ao2);             \
    PF[(WB) * PBUF + woff + 3 * PSTR] = (unsigned short)f2bf(Ao3);             \
    if (rlane) {                                                               \
      c0 += (mw & 0x1u)       ? lr.x : 0.f;                                    \
      c1 += (mw & 0x100u)     ? lr.y : 0.f;                                    \
      c2 += (mw & 0x10000u)   ? lr.z : 0.f;                                    \
      c3 += (mw & 0x1000000u) ? lr.w : 0.f;                                    \
      lr.x = __logf(Cr.x); lr.y = __logf(Cr.y);                                \
      lr.z = __logf(Cr.z); lr.w = __logf(Cr.w);                                \
      f32x4 rv;                                                                \
      rv.x = __builtin_amdgcn_rcpf(Cr.x);                                      \
      rv.y = __builtin_amdgcn_rcpf(Cr.y);                                      \
      rv.z = __builtin_amdgcn_rcpf(Cr.z);                                      \
      rv.w = __builtin_amdgcn_rcpf(Cr.w);                                      \
      *(f32x4*)&r_s[WB][khi << 2] = rv;                                        \
    }                                                                          \
    bar_lgkm();                                                                \
  } while (0)

  for (int t = 1; t < Lc; t += 2) {
    STEP(t, 1, 0, xA0, xA1, xA2, xA3);
    if (t + 1 < Lc) { STEP(t + 1, 0, 1, xB0, xB1, xB2, xB3); }
  }
#undef STEP

  // ---- logZ_b = c_b + log(sum_j Abar[b][j] * exp(end[j])) ----
  if (rlane) {
    f32x4 cv = {c0, c1, c2, c3};
    *(f32x4*)&c_s[khi << 2] = cv;
  }
  float eex = __expf(endT[jloc]);
  float v0 = Ao0 * eex, v1 = Ao1 * eex, v2 = Ao2 * eex, v3 = Ao3 * eex;
#pragma unroll
  for (int off = 1; off < 16; off <<= 1) {
    v0 += __shfl_xor(v0, off);
    v1 += __shfl_xor(v1, off);
    v2 += __shfl_xor(v2, off);
    v3 += __shfl_xor(v3, off);
  }
  if (crow == 0) {
    red[4 * khi + 0][w] = v0;
    red[4 * khi + 1][w] = v1;
    red[4 * khi + 2][w] = v2;
    red[4 * khi + 3][w] = v3;
  }
  __syncthreads();
  if (tid < GB) {
    float tot = 0.f;
#pragma unroll
    for (int ww = 0; ww < NW; ++ww) tot += red[tid][ww];
    float logZ = c_s[tid] + __logf(tot);
    diff_out[bg0 + tid] = logZ - score_s[tid];
    msum_out[bg0 + tid] = msum_s[tid];
  }
}

__global__ __launch_bounds__(512)
void crf_final(const float* __restrict__ diff, const float* __restrict__ msum,
               float* __restrict__ out)
{
  __shared__ float sd[512];
  __shared__ float sm[512];
  int t = threadIdx.x;
  sd[t] = diff[t];
  sm[t] = msum[t];
  __syncthreads();
  for (int s = 256; s > 0; s >>= 1) {
    if (t < s) { sd[t] += sd[t + s]; sm[t] += sm[t + s]; }
    __syncthreads();
  }
  if (t == 0) out[0] = sd[0] / sm[0];
}

extern "C" void kernel_launch(void* const* d_in, const int* in_sizes, int n_in,
                              void* d_out, int out_size, void* d_ws, size_t ws_size,
                              hipStream_t stream) {
  const float* x      = (const float*)d_in[0];
  const float* trans  = (const float*)d_in[1];
  const float* startT = (const float*)d_in[2];
  const float* endT   = (const float*)d_in[3];
  const int*   labels = (const int*)d_in[4];
  const int*   mask   = (const int*)d_in[5];
  float* out = (float*)d_out;
  float* ws  = (float*)d_ws;
  float* diff = ws;        // [512]
  float* msum = ws + Bc;   // [512]

  crf_forward<<<dim3(Bc / GB), dim3(512), 0, stream>>>(
      x, trans, startT, endT, labels, mask, diff, msum);
  crf_final<<<dim3(1), dim3(512), 0, stream>>>(diff, msum, out);
}